// Round 1
// baseline (272.274 us; speedup 1.0000x reference)
//
#include <hip/hip_runtime.h>
#include <hip/hip_bf16.h>
#include <stdint.h>

#define B_DIM   4096
#define IN_DIM  4096
#define OUT_DIM 4096
#define K_SEL   128

typedef unsigned short u16;
typedef __bf16 bf16x8 __attribute__((ext_vector_type(8)));
typedef float  f32x4  __attribute__((ext_vector_type(4)));

static __device__ __forceinline__ u16 f2bf(float f) {
    uint32_t u = __builtin_bit_cast(uint32_t, f);
    uint32_t r = (u + 0x7fffu + ((u >> 16) & 1u)) >> 16;
    return (u16)r;
}

// ---------------------------------------------------------------------------
// K1: column sums of W (fp64 partials over 256-row chunks) + W -> bf16.
// grid: 256 blocks (16 col-chunks x 16 row-chunks) x 256 threads.
// ---------------------------------------------------------------------------
__global__ __launch_bounds__(256) void colsum_conv(const float* __restrict__ W,
                                                   double* __restrict__ part,
                                                   u16* __restrict__ Wb) {
    int cb = blockIdx.x & 15;
    int rb = blockIdx.x >> 4;
    int col = cb * 256 + threadIdx.x;
    int row0 = rb * 256;
    double s = 0.0;
    for (int r = 0; r < 256; ++r) {
        size_t idx = (size_t)(row0 + r) * IN_DIM + col;
        float v = W[idx];
        s += (double)v;
        Wb[idx] = f2bf(v);
    }
    part[(size_t)rb * IN_DIM + col] = s;
}

__global__ __launch_bounds__(256) void colsum_final(const double* __restrict__ part,
                                                    float* __restrict__ cs) {
    int col = blockIdx.x * 256 + threadIdx.x;
    double s = 0.0;
    for (int r = 0; r < 16; ++r) s += part[(size_t)r * IN_DIM + col];
    cs[col] = (float)s;
}

// ---------------------------------------------------------------------------
// K3: per-row top-128 of |x*colsum| via 4-pass radix select on fp32 bits,
// exact tie handling (lowest index first, matching jax.lax.top_k), then
// write masked x as bf16. One block (256 threads) per row; thread t owns
// contiguous elements [t*16, t*16+16).
// ---------------------------------------------------------------------------
__global__ __launch_bounds__(256) void topk_mask(const float* __restrict__ x,
                                                 const float* __restrict__ cs,
                                                 u16* __restrict__ xz) {
    __shared__ uint32_t hist[256];
    __shared__ uint32_t suf[256];
    __shared__ uint32_t s_scan[256];
    __shared__ uint32_t s_prefix, s_krem;

    const int b = blockIdx.x, t = threadIdx.x;
    const float4* xrow = (const float4*)(x + (size_t)b * IN_DIM);
    const float4* csv  = (const float4*)cs;

    float    xr[16];
    uint32_t ul[16];
#pragma unroll
    for (int q = 0; q < 4; ++q) {
        float4 xv = xrow[t * 4 + q];
        float4 cv = csv[t * 4 + q];
        xr[q*4+0] = xv.x; xr[q*4+1] = xv.y; xr[q*4+2] = xv.z; xr[q*4+3] = xv.w;
        ul[q*4+0] = __builtin_bit_cast(uint32_t, xv.x * cv.x) & 0x7fffffffu;
        ul[q*4+1] = __builtin_bit_cast(uint32_t, xv.y * cv.y) & 0x7fffffffu;
        ul[q*4+2] = __builtin_bit_cast(uint32_t, xv.z * cv.z) & 0x7fffffffu;
        ul[q*4+3] = __builtin_bit_cast(uint32_t, xv.w * cv.w) & 0x7fffffffu;
    }
    if (t == 0) { s_prefix = 0u; s_krem = K_SEL; }
    __syncthreads();

    // 4 radix passes, high byte first
#pragma unroll
    for (int p = 3; p >= 0; --p) {
        const int sh = p * 8;
        const uint32_t hi_mask = (p == 3) ? 0u : (0xFFFFFFFFu << (sh + 8));
        const uint32_t prefix = s_prefix;     // written before pass-start barrier
        const uint32_t krem   = s_krem;
        hist[t] = 0u;
        __syncthreads();
#pragma unroll
        for (int j = 0; j < 16; ++j) {
            uint32_t u = ul[j];
            if ((u & hi_mask) == (prefix & hi_mask))
                atomicAdd(&hist[(u >> sh) & 255u], 1u);
        }
        __syncthreads();
        // suffix sum: suf[d] = sum_{d' >= d} hist[d']
        uint32_t mine = hist[t];
        suf[t] = mine;
        __syncthreads();
#pragma unroll
        for (int off = 1; off < 256; off <<= 1) {
            uint32_t other = (t + off < 256) ? suf[t + off] : 0u;
            __syncthreads();
            mine += other;
            suf[t] = mine;
            __syncthreads();
        }
        uint32_t mysuf   = suf[t];
        uint32_t nextsuf = (t < 255) ? suf[t + 1] : 0u;
        if (mysuf >= krem && (t == 255 || nextsuf < krem)) {
            s_prefix = prefix | ((uint32_t)t << sh);
            s_krem   = krem - nextsuf;
        }
        __syncthreads();
    }
    const uint32_t T       = s_prefix;      // exact value of the 128th largest
    const uint32_t need_eq = s_krem;        // how many ==T to drop (lowest index first)

    // stable enumeration of ==T elements in index order
    int cnt = 0;
#pragma unroll
    for (int j = 0; j < 16; ++j) cnt += (ul[j] == T) ? 1 : 0;
    s_scan[t] = (uint32_t)cnt;
    __syncthreads();
    uint32_t inc = (uint32_t)cnt;
#pragma unroll
    for (int off = 1; off < 256; off <<= 1) {
        uint32_t other = (t >= off) ? s_scan[t - off] : 0u;
        __syncthreads();
        inc += other;
        s_scan[t] = inc;
        __syncthreads();
    }
    const int base = (int)(inc - (uint32_t)cnt);

    union { u16 us[16]; uint4 v[2]; } ob;
    int eqseen = 0;
#pragma unroll
    for (int j = 0; j < 16; ++j) {
        uint32_t u = ul[j];
        bool drop = (u > T);
        if (u == T) {
            if (base + eqseen < (int)need_eq) drop = true;
            ++eqseen;
        }
        ob.us[j] = drop ? (u16)0 : f2bf(xr[j]);
    }
    uint4* dst = (uint4*)(xz + (size_t)b * IN_DIM + t * 16);
    dst[0] = ob.v[0];
    dst[1] = ob.v[1];
}

// ---------------------------------------------------------------------------
// K4: bf16 GEMM, C = A @ B^T  (A=[M][K] xz, B=[N][K] Wb, C=[M][N] fp32).
// m97 structure: 128x128 tile, BK=64, 4 waves (2x2), global_load_lds width 16,
// mfma_f32_16x16x32_bf16, XCD-aware block swizzle.
// ---------------------------------------------------------------------------
#define BM  128
#define BN  128
#define BKT 64

__global__ __launch_bounds__(256) void gemm_bt(const u16* __restrict__ A,
                                               const u16* __restrict__ Bm,
                                               float* __restrict__ C) {
    __shared__ u16 As[BM * BKT];   // 16 KB, row-major [128][64]
    __shared__ u16 Bs[BN * BKT];   // 16 KB

    int bid = blockIdx.x;
    // 1024 blocks, 8 XCDs -> bijective chunked swizzle (1024 % 8 == 0)
    int swz = (bid & 7) * 128 + (bid >> 3);
    int bm = swz >> 5, bn = swz & 31;
    int m0 = bm * BM, n0 = bn * BN;

    int t = threadIdx.x;
    int w = t >> 6, l = t & 63;
    int lr = l & 15, lk = l >> 4;
    int wm = w >> 1, wn = w & 1;

    f32x4 acc[4][4];
#pragma unroll
    for (int i = 0; i < 4; ++i)
#pragma unroll
        for (int j = 0; j < 4; ++j)
            acc[i][j] = f32x4{0.f, 0.f, 0.f, 0.f};

    const int srow = l >> 3;        // 0..7  (row within 8-row segment)
    const int scol = (l & 7) * 8;   // 0..56 (element col of 16B chunk)

    for (int kt = 0; kt < IN_DIM; kt += BKT) {
        __syncthreads();   // previous tile's compute done before overwrite
#pragma unroll
        for (int j = 0; j < 4; ++j) {
            int s = j * 4 + w;                  // 1KB segment id 0..15
            int rowA = s * 8 + srow;
            const u16* gA = A  + (size_t)(m0 + rowA) * IN_DIM + kt + scol;
            const u16* gB = Bm + (size_t)(n0 + rowA) * IN_DIM + kt + scol;
            __builtin_amdgcn_global_load_lds(
                (const __attribute__((address_space(1))) void*)gA,
                (__attribute__((address_space(3))) void*)((char*)As + s * 1024),
                16, 0, 0);
            __builtin_amdgcn_global_load_lds(
                (const __attribute__((address_space(1))) void*)gB,
                (__attribute__((address_space(3))) void*)((char*)Bs + s * 1024),
                16, 0, 0);
        }
        __syncthreads();   // staging complete (compiler drains vmcnt at barrier)

#pragma unroll
        for (int kk = 0; kk < BKT; kk += 32) {
            bf16x8 af[4], bfr[4];
#pragma unroll
            for (int mi = 0; mi < 4; ++mi)
                af[mi] = *(const bf16x8*)&As[(wm * 64 + mi * 16 + lr) * BKT + kk + lk * 8];
#pragma unroll
            for (int ni = 0; ni < 4; ++ni)
                bfr[ni] = *(const bf16x8*)&Bs[(wn * 64 + ni * 16 + lr) * BKT + kk + lk * 8];
#pragma unroll
            for (int mi = 0; mi < 4; ++mi)
#pragma unroll
                for (int ni = 0; ni < 4; ++ni)
                    acc[mi][ni] = __builtin_amdgcn_mfma_f32_16x16x32_bf16(
                        af[mi], bfr[ni], acc[mi][ni], 0, 0, 0);
        }
    }

    // epilogue: C/D layout col = lane&15, row = (lane>>4)*4 + reg
#pragma unroll
    for (int mi = 0; mi < 4; ++mi)
#pragma unroll
        for (int ni = 0; ni < 4; ++ni)
#pragma unroll
            for (int r = 0; r < 4; ++r) {
                int row = m0 + wm * 64 + mi * 16 + lk * 4 + r;
                int col = n0 + wn * 64 + ni * 16 + lr;
                C[(size_t)row * OUT_DIM + col] = acc[mi][ni][r];
            }
}

// ---------------------------------------------------------------------------
extern "C" void kernel_launch(void* const* d_in, const int* in_sizes, int n_in,
                              void* d_out, int out_size, void* d_ws, size_t ws_size,
                              hipStream_t stream) {
    const float* x = (const float*)d_in[0];
    const float* W = (const float*)d_in[1];
    float* out = (float*)d_out;

    char* ws = (char*)d_ws;
    u16*    Wb   = (u16*)ws;                                   // 32 MB bf16 W
    u16*    xz   = (u16*)(ws + (size_t)32 * 1024 * 1024);      // 32 MB bf16 masked x
    float*  cs   = (float*)(ws + (size_t)64 * 1024 * 1024);    // 16 KB colsum
    double* part = (double*)(ws + (size_t)64 * 1024 * 1024 + 16 * 1024); // 512 KB partials

    colsum_conv<<<256, 256, 0, stream>>>(W, part, Wb);
    colsum_final<<<16, 256, 0, stream>>>(part, cs);
    topk_mask<<<4096, 256, 0, stream>>>(x, cs, xz);
    gemm_bt<<<1024, 256, 0, stream>>>(xz, Wb, out);
}

// Round 2
// 211.563 us; speedup vs baseline: 1.2870x; 1.2870x over previous
//
#include <hip/hip_runtime.h>
#include <hip/hip_bf16.h>
#include <stdint.h>

#define B_DIM   4096
#define IN_DIM  4096
#define OUT_DIM 4096
#define K_SEL   128

typedef unsigned short u16;
typedef __bf16 bf16x8 __attribute__((ext_vector_type(8)));
typedef float  f32x4  __attribute__((ext_vector_type(4)));

static __device__ __forceinline__ u16 f2bf(float f) {
    uint32_t u = __builtin_bit_cast(uint32_t, f);
    uint32_t r = (u + 0x7fffu + ((u >> 16) & 1u)) >> 16;
    return (u16)r;
}

// ---------------------------------------------------------------------------
// K1: column sums of W (fp64 partials over 256-row chunks) + W -> bf16.
// ---------------------------------------------------------------------------
__global__ __launch_bounds__(256) void colsum_conv(const float* __restrict__ W,
                                                   double* __restrict__ part,
                                                   u16* __restrict__ Wb) {
    int cb = blockIdx.x & 15;
    int rb = blockIdx.x >> 4;
    int col = cb * 256 + threadIdx.x;
    int row0 = rb * 256;
    double s = 0.0;
    for (int r = 0; r < 256; ++r) {
        size_t idx = (size_t)(row0 + r) * IN_DIM + col;
        float v = W[idx];
        s += (double)v;
        Wb[idx] = f2bf(v);
    }
    part[(size_t)rb * IN_DIM + col] = s;
}

__global__ __launch_bounds__(256) void colsum_final(const double* __restrict__ part,
                                                    float* __restrict__ cs) {
    int col = blockIdx.x * 256 + threadIdx.x;
    double s = 0.0;
    for (int r = 0; r < 16; ++r) s += part[(size_t)r * IN_DIM + col];
    cs[col] = (float)s;
}

// ---------------------------------------------------------------------------
// K3: per-row top-128 of |x*colsum| via 4-pass radix select, exact ties
// (lowest index first), write masked x as bf16. One 256-thread block per row.
// ---------------------------------------------------------------------------
__global__ __launch_bounds__(256) void topk_mask(const float* __restrict__ x,
                                                 const float* __restrict__ cs,
                                                 u16* __restrict__ xz) {
    __shared__ uint32_t hist[256];
    __shared__ uint32_t suf[256];
    __shared__ uint32_t s_scan[256];
    __shared__ uint32_t s_prefix, s_krem;

    const int b = blockIdx.x, t = threadIdx.x;
    const float4* xrow = (const float4*)(x + (size_t)b * IN_DIM);
    const float4* csv  = (const float4*)cs;

    float    xr[16];
    uint32_t ul[16];
#pragma unroll
    for (int q = 0; q < 4; ++q) {
        float4 xv = xrow[t * 4 + q];
        float4 cv = csv[t * 4 + q];
        xr[q*4+0] = xv.x; xr[q*4+1] = xv.y; xr[q*4+2] = xv.z; xr[q*4+3] = xv.w;
        ul[q*4+0] = __builtin_bit_cast(uint32_t, xv.x * cv.x) & 0x7fffffffu;
        ul[q*4+1] = __builtin_bit_cast(uint32_t, xv.y * cv.y) & 0x7fffffffu;
        ul[q*4+2] = __builtin_bit_cast(uint32_t, xv.z * cv.z) & 0x7fffffffu;
        ul[q*4+3] = __builtin_bit_cast(uint32_t, xv.w * cv.w) & 0x7fffffffu;
    }
    if (t == 0) { s_prefix = 0u; s_krem = K_SEL; }
    __syncthreads();

#pragma unroll
    for (int p = 3; p >= 0; --p) {
        const int sh = p * 8;
        const uint32_t hi_mask = (p == 3) ? 0u : (0xFFFFFFFFu << (sh + 8));
        const uint32_t prefix = s_prefix;
        const uint32_t krem   = s_krem;
        hist[t] = 0u;
        __syncthreads();
#pragma unroll
        for (int j = 0; j < 16; ++j) {
            uint32_t u = ul[j];
            if ((u & hi_mask) == (prefix & hi_mask))
                atomicAdd(&hist[(u >> sh) & 255u], 1u);
        }
        __syncthreads();
        uint32_t mine = hist[t];
        suf[t] = mine;
        __syncthreads();
#pragma unroll
        for (int off = 1; off < 256; off <<= 1) {
            uint32_t other = (t + off < 256) ? suf[t + off] : 0u;
            __syncthreads();
            mine += other;
            suf[t] = mine;
            __syncthreads();
        }
        uint32_t mysuf   = suf[t];
        uint32_t nextsuf = (t < 255) ? suf[t + 1] : 0u;
        if (mysuf >= krem && (t == 255 || nextsuf < krem)) {
            s_prefix = prefix | ((uint32_t)t << sh);
            s_krem   = krem - nextsuf;
        }
        __syncthreads();
    }
    const uint32_t T       = s_prefix;
    const uint32_t need_eq = s_krem;

    int cnt = 0;
#pragma unroll
    for (int j = 0; j < 16; ++j) cnt += (ul[j] == T) ? 1 : 0;
    s_scan[t] = (uint32_t)cnt;
    __syncthreads();
    uint32_t inc = (uint32_t)cnt;
#pragma unroll
    for (int off = 1; off < 256; off <<= 1) {
        uint32_t other = (t >= off) ? s_scan[t - off] : 0u;
        __syncthreads();
        inc += other;
        s_scan[t] = inc;
        __syncthreads();
    }
    const int base = (int)(inc - (uint32_t)cnt);

    union { u16 us[16]; uint4 v[2]; } ob;
    int eqseen = 0;
#pragma unroll
    for (int j = 0; j < 16; ++j) {
        uint32_t u = ul[j];
        bool drop = (u > T);
        if (u == T) {
            if (base + eqseen < (int)need_eq) drop = true;
            ++eqseen;
        }
        ob.us[j] = drop ? (u16)0 : f2bf(xr[j]);
    }
    uint4* dst = (uint4*)(xz + (size_t)b * IN_DIM + t * 16);
    dst[0] = ob.v[0];
    dst[1] = ob.v[1];
}

// ---------------------------------------------------------------------------
// K4: bf16 GEMM C = A @ B^T, 256x256 tile, BK=64, 8 waves (2Mx4N), 8-phase
// schedule (T3+T4 counted vmcnt(6)), T2 XOR-swizzle (col ^= (row&7)<<3) via
// pre-swizzled global source + swizzled ds_read, T5 setprio around MFMA.
// LDS 128KB: per buf {A-half0, A-half1, B-stripe0, B-stripe1} x 16KB regions.
// B region qn packs rows with bit5==qn: local = (row>>6)*32 + (row&31).
// Race-free by construction: each stage targets a region whose last ds_read
// drained >=1 barrier earlier; each read covered by a prior vmcnt(6)+barrier.
// ---------------------------------------------------------------------------
#define NT 64   // K-tiles of 64

__global__ __launch_bounds__(512, 2) void gemm_8ph(const u16* __restrict__ A,
                                                   const u16* __restrict__ Bm,
                                                   float* __restrict__ C) {
    __shared__ u16 lds_[2 * 4 * 8192];   // 131072 B

    const int bid = blockIdx.x;
    const int swz = (bid & 7) * 32 + (bid >> 3);   // 256 blocks, 8 XCDs
    const int m0 = (swz >> 4) * 256, n0 = (swz & 15) * 256;

    const int t = threadIdx.x;
    const int w = t >> 6, l = t & 63;
    const int lr = l & 15, lk = l >> 4;
    const int wm = w >> 2, wn = w & 3;

    const int e3   = (lr & 7) << 3;
    const int col0 = (lk << 3) ^ e3;                 // swizzled col (elems), ks=0
    const int cswz = ((l & 7) ^ (l >> 3)) * 8;       // staging src col (elems)

    f32x4 acc[8][4];
#pragma unroll
    for (int i = 0; i < 8; ++i)
#pragma unroll
        for (int j = 0; j < 4; ++j) acc[i][j] = f32x4{0.f, 0.f, 0.f, 0.f};

#define GLOAD(g, off_bytes)                                                     \
    __builtin_amdgcn_global_load_lds(                                           \
        (const __attribute__((address_space(1))) void*)(g),                     \
        (__attribute__((address_space(3))) void*)(((char*)lds_) + (off_bytes)), \
        16, 0, 0)

    // stage A half j, sub-quadrant q (rows q*64..q*64+63), K-tile col kt
    auto stageA = [&](int bufn, int j, int q, int kt) {
        int off = ((bufn * 4 + j) * 16384) + q * 8192 + w * 1024;
        const u16* g = A + (size_t)(m0 + j * 128 + q * 64 + w * 8 + (l >> 3)) * IN_DIM
                         + kt + cswz;
        GLOAD(g, off);
    };
    // stage B stripe qn, half j (local rows j*64..j*64+63)
    auto stageB = [&](int bufn, int qn, int j, int kt) {
        int off = ((bufn * 4 + 2 + qn) * 16384) + j * 8192 + w * 1024;
        const u16* g = Bm + (size_t)(n0 + (j * 2 + (w >> 2)) * 64 + qn * 32
                                     + (w & 3) * 8 + (l >> 3)) * IN_DIM
                          + kt + cswz;
        GLOAD(g, off);
    };

    // prologue: K0 complete + K1 {Aq0, Bq0}; wait all K0 (4 newest in flight)
    stageA(0, 0, 0, 0);  stageA(0, 1, 0, 0);
    stageA(0, 0, 1, 0);  stageA(0, 1, 1, 0);
    stageB(0, 0, 0, 0);  stageB(0, 0, 1, 0);
    stageB(0, 1, 0, 0);  stageB(0, 1, 1, 0);
    stageA(1, 0, 0, 64); stageA(1, 1, 0, 64);
    stageB(1, 0, 0, 64); stageB(1, 0, 1, 64);
    asm volatile("s_waitcnt vmcnt(4)" ::: "memory");
    __builtin_amdgcn_s_barrier();
    asm volatile("" ::: "memory");

    for (int u = 0; u < NT; ++u) {
        const int buf = u & 1, bufn = buf ^ 1;
        const int kt1 = (u + 1) * 64, kt2 = (u + 2) * 64;
        const int regA = (buf * 4 + wm) * 8192 + lr * 64;
#pragma unroll
        for (int p = 0; p < 4; ++p) {
            const int qm = p >> 1, qn = p & 1;
            // --- register subtile ds-reads (12x ds_read_b128, swizzled) ---
            bf16x8 a[4][2], b[2][2];
            const int ra = regA + qm * 4096;
#pragma unroll
            for (int mi = 0; mi < 4; ++mi) {
                a[mi][0] = *(const bf16x8*)&lds_[ra + mi * 1024 + col0];
                a[mi][1] = *(const bf16x8*)&lds_[ra + mi * 1024 + (col0 ^ 32)];
            }
            const int rbq = (buf * 4 + 2 + qn) * 8192 + (wn * 32 + lr) * 64;
#pragma unroll
            for (int ni = 0; ni < 2; ++ni) {
                b[ni][0] = *(const bf16x8*)&lds_[rbq + ni * 1024 + col0];
                b[ni][1] = *(const bf16x8*)&lds_[rbq + ni * 1024 + (col0 ^ 32)];
            }
            // --- stage one 16KB unit (2 x global_load_lds) ---
            if (p == 0)      { if (u < NT - 1) { stageA(bufn, 0, 1, kt1); stageA(bufn, 1, 1, kt1); } }
            else if (p == 1) { if (u < NT - 1) { stageB(bufn, 1, 0, kt1); stageB(bufn, 1, 1, kt1); } }
            else if (p == 2) { if (u < NT - 2) { stageA(buf,  0, 0, kt2); stageA(buf,  1, 0, kt2); } }
            else             { if (u < NT - 2) { stageB(buf,  0, 0, kt2); stageB(buf,  0, 1, kt2); } }
            asm volatile("" ::: "memory");
            __builtin_amdgcn_s_barrier();
            asm volatile("s_waitcnt lgkmcnt(0)" ::: "memory");
            __builtin_amdgcn_sched_barrier(0);
            __builtin_amdgcn_s_setprio(1);
#pragma unroll
            for (int mi = 0; mi < 4; ++mi)
#pragma unroll
                for (int ni = 0; ni < 2; ++ni) {
                    acc[qm*4+mi][qn*2+ni] = __builtin_amdgcn_mfma_f32_16x16x32_bf16(
                        a[mi][0], b[ni][0], acc[qm*4+mi][qn*2+ni], 0, 0, 0);
                    acc[qm*4+mi][qn*2+ni] = __builtin_amdgcn_mfma_f32_16x16x32_bf16(
                        a[mi][1], b[ni][1], acc[qm*4+mi][qn*2+ni], 0, 0, 0);
                }
            __builtin_amdgcn_s_setprio(0);
            __builtin_amdgcn_sched_barrier(0);
            if (p == 0 || p == 3) {
                asm volatile("s_waitcnt vmcnt(6)" ::: "memory");
            }
            asm volatile("" ::: "memory");
            __builtin_amdgcn_s_barrier();
            asm volatile("" ::: "memory");
        }
    }
#undef GLOAD

    // epilogue: C/D layout col = lane&15, row = (lane>>4)*4 + r
#pragma unroll
    for (int gmi = 0; gmi < 8; ++gmi)
#pragma unroll
        for (int gni = 0; gni < 4; ++gni)
#pragma unroll
            for (int r = 0; r < 4; ++r) {
                int row = m0 + wm * 128 + gmi * 16 + lk * 4 + r;
                int col = n0 + wn * 64 + gni * 16 + lr;
                C[(size_t)row * OUT_DIM + col] = acc[gmi][gni][r];
            }
}

// ---------------------------------------------------------------------------
extern "C" void kernel_launch(void* const* d_in, const int* in_sizes, int n_in,
                              void* d_out, int out_size, void* d_ws, size_t ws_size,
                              hipStream_t stream) {
    const float* x = (const float*)d_in[0];
    const float* W = (const float*)d_in[1];
    float* out = (float*)d_out;

    char* ws = (char*)d_ws;
    u16*    Wb   = (u16*)ws;                                   // 32 MB bf16 W
    u16*    xz   = (u16*)(ws + (size_t)32 * 1024 * 1024);      // 32 MB bf16 masked x
    float*  cs   = (float*)(ws + (size_t)64 * 1024 * 1024);    // 16 KB colsum
    double* part = (double*)(ws + (size_t)64 * 1024 * 1024 + 16 * 1024); // 512 KB partials

    colsum_conv<<<256, 256, 0, stream>>>(W, part, Wb);
    colsum_final<<<16, 256, 0, stream>>>(part, cs);
    topk_mask<<<4096, 256, 0, stream>>>(x, cs, xz);
    gemm_8ph<<<256, 512, 0, stream>>>(xz, Wb, out);
}

// Round 3
// 195.163 us; speedup vs baseline: 1.3951x; 1.0840x over previous
//
#include <hip/hip_runtime.h>
#include <hip/hip_bf16.h>
#include <stdint.h>

#define B_DIM   4096
#define IN_DIM  4096
#define OUT_DIM 4096
#define K_SEL   128

typedef unsigned short u16;
typedef __bf16 bf16x8 __attribute__((ext_vector_type(8)));
typedef float  f32x4  __attribute__((ext_vector_type(4)));

static __device__ __forceinline__ u16 f2bf(float f) {
    uint32_t u = __builtin_bit_cast(uint32_t, f);
    uint32_t r = (u + 0x7fffu + ((u >> 16) & 1u)) >> 16;
    return (u16)r;
}

// ---------------------------------------------------------------------------
// K1: column sums of W (fp64 partials over 32-row chunks) + W -> bf16.
// 2048 blocks = (16 col-chunks x 128 row-chunks) x 256 threads.
// part[] lives in d_out (4 MB; consumed by colsum_final before gemm writes).
// ---------------------------------------------------------------------------
__global__ __launch_bounds__(256) void colsum_conv(const float* __restrict__ W,
                                                   double* __restrict__ part,
                                                   u16* __restrict__ Wb) {
    int cb = blockIdx.x & 15;
    int rb = blockIdx.x >> 4;          // 0..127
    int col = cb * 256 + threadIdx.x;
    int row0 = rb * 32;
    double s = 0.0;
    for (int r = 0; r < 32; ++r) {
        size_t idx = (size_t)(row0 + r) * IN_DIM + col;
        float v = W[idx];
        s += (double)v;
        Wb[idx] = f2bf(v);
    }
    part[(size_t)rb * IN_DIM + col] = s;
}

__global__ __launch_bounds__(256) void colsum_final(const double* __restrict__ part,
                                                    float* __restrict__ cs) {
    int col = blockIdx.x * 256 + threadIdx.x;
    double s = 0.0;
    for (int r = 0; r < 128; ++r) s += part[(size_t)r * IN_DIM + col];
    cs[col] = (float)s;
}

// ---------------------------------------------------------------------------
// K3: per-row top-128 of |x*colsum| via 4-pass radix select, exact ties
// (lowest index first), write masked x as bf16. One 256-thread block per row.
// ---------------------------------------------------------------------------
__global__ __launch_bounds__(256) void topk_mask(const float* __restrict__ x,
                                                 const float* __restrict__ cs,
                                                 u16* __restrict__ xz) {
    __shared__ uint32_t hist[256];
    __shared__ uint32_t suf[256];
    __shared__ uint32_t s_scan[256];
    __shared__ uint32_t s_prefix, s_krem;

    const int b = blockIdx.x, t = threadIdx.x;
    const float4* xrow = (const float4*)(x + (size_t)b * IN_DIM);
    const float4* csv  = (const float4*)cs;

    float    xr[16];
    uint32_t ul[16];
#pragma unroll
    for (int q = 0; q < 4; ++q) {
        float4 xv = xrow[t * 4 + q];
        float4 cv = csv[t * 4 + q];
        xr[q*4+0] = xv.x; xr[q*4+1] = xv.y; xr[q*4+2] = xv.z; xr[q*4+3] = xv.w;
        ul[q*4+0] = __builtin_bit_cast(uint32_t, xv.x * cv.x) & 0x7fffffffu;
        ul[q*4+1] = __builtin_bit_cast(uint32_t, xv.y * cv.y) & 0x7fffffffu;
        ul[q*4+2] = __builtin_bit_cast(uint32_t, xv.z * cv.z) & 0x7fffffffu;
        ul[q*4+3] = __builtin_bit_cast(uint32_t, xv.w * cv.w) & 0x7fffffffu;
    }
    if (t == 0) { s_prefix = 0u; s_krem = K_SEL; }
    __syncthreads();

#pragma unroll
    for (int p = 3; p >= 0; --p) {
        const int sh = p * 8;
        const uint32_t hi_mask = (p == 3) ? 0u : (0xFFFFFFFFu << (sh + 8));
        const uint32_t prefix = s_prefix;
        const uint32_t krem   = s_krem;
        hist[t] = 0u;
        __syncthreads();
#pragma unroll
        for (int j = 0; j < 16; ++j) {
            uint32_t u = ul[j];
            if ((u & hi_mask) == (prefix & hi_mask))
                atomicAdd(&hist[(u >> sh) & 255u], 1u);
        }
        __syncthreads();
        uint32_t mine = hist[t];
        suf[t] = mine;
        __syncthreads();
#pragma unroll
        for (int off = 1; off < 256; off <<= 1) {
            uint32_t other = (t + off < 256) ? suf[t + off] : 0u;
            __syncthreads();
            mine += other;
            suf[t] = mine;
            __syncthreads();
        }
        uint32_t mysuf   = suf[t];
        uint32_t nextsuf = (t < 255) ? suf[t + 1] : 0u;
        if (mysuf >= krem && (t == 255 || nextsuf < krem)) {
            s_prefix = prefix | ((uint32_t)t << sh);
            s_krem   = krem - nextsuf;
        }
        __syncthreads();
    }
    const uint32_t T       = s_prefix;
    const uint32_t need_eq = s_krem;

    int cnt = 0;
#pragma unroll
    for (int j = 0; j < 16; ++j) cnt += (ul[j] == T) ? 1 : 0;
    s_scan[t] = (uint32_t)cnt;
    __syncthreads();
    uint32_t inc = (uint32_t)cnt;
#pragma unroll
    for (int off = 1; off < 256; off <<= 1) {
        uint32_t other = (t >= off) ? s_scan[t - off] : 0u;
        __syncthreads();
        inc += other;
        s_scan[t] = inc;
        __syncthreads();
    }
    const int base = (int)(inc - (uint32_t)cnt);

    union { u16 us[16]; uint4 v[2]; } ob;
    int eqseen = 0;
#pragma unroll
    for (int j = 0; j < 16; ++j) {
        uint32_t u = ul[j];
        bool drop = (u > T);
        if (u == T) {
            if (base + eqseen < (int)need_eq) drop = true;
            ++eqseen;
        }
        ob.us[j] = drop ? (u16)0 : f2bf(xr[j]);
    }
    uint4* dst = (uint4*)(xz + (size_t)b * IN_DIM + t * 16);
    dst[0] = ob.v[0];
    dst[1] = ob.v[1];
}

// ---------------------------------------------------------------------------
// K4: bf16 GEMM C = A @ B^T, 256x256 tile, BK=64, 8 waves (2Mx4N).
// Phase (q, ks): 8 ds_read_b128 (4 A-frags from subblock wm*2+q, 4 B-frags
// from subblock wn) -> 16 independent MFMAs (reuse 4x; LDS wall ~770cyc vs
// MFMA wall ~620cyc). T2 XOR-swizzle (zero conflicts), raw s_barrier pairs,
// lgkmcnt(0)+sched_barrier (rule #18), setprio around MFMA (T5), single
// counted vmcnt(2) per K-tile at p3 (T4).
// LDS per buf (64KB): A = 4 x 8KB subblocks (64 rows x 64 cols), B same.
// Staging: p0: B01+A13(k+1) | p1: B23(k+1) | p2: A02(k+2, kt clamped) | p3: -
// Race-free: each staged region's last read drained >=1 barrier earlier;
// vmcnt(2)@p3 leaves only p2's A02 prefetch in flight (verified incl. tail).
// ---------------------------------------------------------------------------
#define NT 64

__global__ __launch_bounds__(512, 2) void gemm_8ph(const u16* __restrict__ A,
                                                   const u16* __restrict__ Bm,
                                                   float* __restrict__ C) {
    __shared__ u16 lds_[65536];   // 128 KB

    const int bid = blockIdx.x;
    const int swz = (bid & 7) * 32 + (bid >> 3);   // 256 blocks, 8 XCDs
    const int m0 = (swz >> 4) * 256, n0 = (swz & 15) * 256;

    const int t = threadIdx.x;
    const int w = t >> 6, l = t & 63;
    const int lr = l & 15, lk = l >> 4;
    const int wm = w >> 2, wn = w & 3;

    const int cswz = ((t & 7) ^ ((t >> 3) & 7)) * 8;   // staging src col (elems)
    const int colA = (lk * 8) ^ ((lr & 7) * 8);        // swizzled read col, ks=0

    f32x4 acc[8][4];
#pragma unroll
    for (int i = 0; i < 8; ++i)
#pragma unroll
        for (int j = 0; j < 4; ++j) acc[i][j] = f32x4{0.f, 0.f, 0.f, 0.f};

#define GLOAD(g, off_bytes)                                                     \
    __builtin_amdgcn_global_load_lds(                                           \
        (const __attribute__((address_space(1))) void*)(g),                     \
        (__attribute__((address_space(3))) void*)(((char*)lds_) + (off_bytes)), \
        16, 0, 0)

    // stage A/B subblock s (64 rows x 64 cols, 8KB) of K-tile at col kt
    auto stA = [&](int kb, int s, int kt) {
        GLOAD(A + (size_t)(m0 + s * 64 + (t >> 3)) * IN_DIM + kt + cswz,
              kb * 65536 + s * 8192 + t * 16);
    };
    auto stB = [&](int kb, int s, int kt) {
        GLOAD(Bm + (size_t)(n0 + s * 64 + (t >> 3)) * IN_DIM + kt + cswz,
              kb * 65536 + 32768 + s * 8192 + t * 16);
    };

    // prologue: all of tile 0, then A02(1); wait all but the newest 2
    stA(0, 0, 0); stA(0, 1, 0); stA(0, 2, 0); stA(0, 3, 0);
    stB(0, 0, 0); stB(0, 1, 0); stB(0, 2, 0); stB(0, 3, 0);
    stA(1, 0, 64); stA(1, 2, 64);
    asm volatile("s_waitcnt vmcnt(2)" ::: "memory");
    __builtin_amdgcn_s_barrier();
    asm volatile("" ::: "memory");

    for (int k = 0; k < NT; ++k) {
        const int buf = k & 1, bufn = buf ^ 1;
        const int kt1 = (k + 1) * 64;
        const int ktc = (k + 2 < NT ? k + 2 : NT - 1) * 64;  // clamped (keeps
        // in-flight count schedule-exact at the tail; clamped data never read)
        const int Ab = buf * 32768 + (wm * 2) * 4096;        // elems
        const int Bb = buf * 32768 + 16384 + wn * 4096;      // elems
#pragma unroll
        for (int p = 0; p < 4; ++p) {
            const int q = p >> 1, ks = p & 1;
            const int col = colA ^ (ks * 32);
            bf16x8 a[4], b[4];
            const int ra = Ab + q * 4096 + lr * 64 + col;
#pragma unroll
            for (int mi = 0; mi < 4; ++mi)
                a[mi] = *(const bf16x8*)&lds_[ra + mi * 1024];
            const int rb = Bb + lr * 64 + col;
#pragma unroll
            for (int ni = 0; ni < 4; ++ni)
                b[ni] = *(const bf16x8*)&lds_[rb + ni * 1024];

            if (p == 0) {
                if (k < NT - 1) { stB(bufn, 0, kt1); stB(bufn, 1, kt1);
                                  stA(bufn, 1, kt1); stA(bufn, 3, kt1); }
            } else if (p == 1) {
                if (k < NT - 1) { stB(bufn, 2, kt1); stB(bufn, 3, kt1); }
            } else if (p == 2) {
                stA(buf, 0, ktc); stA(buf, 2, ktc);
            }
            asm volatile("" ::: "memory");
            __builtin_amdgcn_s_barrier();
            asm volatile("s_waitcnt lgkmcnt(0)" ::: "memory");
            __builtin_amdgcn_sched_barrier(0);
            __builtin_amdgcn_s_setprio(1);
#pragma unroll
            for (int mi = 0; mi < 4; ++mi)
#pragma unroll
                for (int ni = 0; ni < 4; ++ni)
                    acc[q * 4 + mi][ni] = __builtin_amdgcn_mfma_f32_16x16x32_bf16(
                        a[mi], b[ni], acc[q * 4 + mi][ni], 0, 0, 0);
            __builtin_amdgcn_s_setprio(0);
            __builtin_amdgcn_sched_barrier(0);
            if (p == 3) asm volatile("s_waitcnt vmcnt(2)" ::: "memory");
            asm volatile("" ::: "memory");
            __builtin_amdgcn_s_barrier();
            asm volatile("" ::: "memory");
        }
    }
#undef GLOAD

    // epilogue: C/D layout col = lane&15, row = (lane>>4)*4 + r
#pragma unroll
    for (int gmi = 0; gmi < 8; ++gmi)
#pragma unroll
        for (int ni = 0; ni < 4; ++ni)
#pragma unroll
            for (int r = 0; r < 4; ++r) {
                int row = m0 + wm * 128 + (gmi >> 2) * 64 + (gmi & 3) * 16 + lk * 4 + r;
                int col = n0 + wn * 64 + ni * 16 + lr;
                C[(size_t)row * OUT_DIM + col] = acc[gmi][ni][r];
            }
}

// ---------------------------------------------------------------------------
extern "C" void kernel_launch(void* const* d_in, const int* in_sizes, int n_in,
                              void* d_out, int out_size, void* d_ws, size_t ws_size,
                              hipStream_t stream) {
    const float* x = (const float*)d_in[0];
    const float* W = (const float*)d_in[1];
    float* out = (float*)d_out;

    char* ws = (char*)d_ws;
    u16*    Wb   = (u16*)ws;                                   // 32 MB bf16 W
    u16*    xz   = (u16*)(ws + (size_t)32 * 1024 * 1024);      // 32 MB bf16 masked x
    float*  cs   = (float*)(ws + (size_t)64 * 1024 * 1024);    // 16 KB colsum
    double* part = (double*)d_out;  // 4 MB partials, consumed before gemm writes

    colsum_conv<<<2048, 256, 0, stream>>>(W, part, Wb);
    colsum_final<<<16, 256, 0, stream>>>(part, cs);
    topk_mask<<<4096, 256, 0, stream>>>(x, cs, xz);
    gemm_8ph<<<256, 512, 0, stream>>>(xz, Wb, out);
}

// Round 4
// 189.311 us; speedup vs baseline: 1.4382x; 1.0309x over previous
//
#include <hip/hip_runtime.h>
#include <hip/hip_bf16.h>
#include <stdint.h>

#define B_DIM   4096
#define IN_DIM  4096
#define OUT_DIM 4096
#define K_SEL   128

typedef unsigned short u16;
typedef __bf16 bf16x8 __attribute__((ext_vector_type(8)));
typedef float  f32x4  __attribute__((ext_vector_type(4)));

static __device__ __forceinline__ u16 f2bf(float f) {
    uint32_t u = __builtin_bit_cast(uint32_t, f);
    uint32_t r = (u + 0x7fffu + ((u >> 16) & 1u)) >> 16;
    return (u16)r;
}

// ---------------------------------------------------------------------------
// K1: column sums of W (fp64 partials over 32-row chunks) + W -> bf16.
// part[] lives in d_out (4 MB; consumed by colsum_final before gemm writes).
// ---------------------------------------------------------------------------
__global__ __launch_bounds__(256) void colsum_conv(const float* __restrict__ W,
                                                   double* __restrict__ part,
                                                   u16* __restrict__ Wb) {
    int cb = blockIdx.x & 15;
    int rb = blockIdx.x >> 4;          // 0..127
    int col = cb * 256 + threadIdx.x;
    int row0 = rb * 32;
    double s = 0.0;
    for (int r = 0; r < 32; ++r) {
        size_t idx = (size_t)(row0 + r) * IN_DIM + col;
        float v = W[idx];
        s += (double)v;
        Wb[idx] = f2bf(v);
    }
    part[(size_t)rb * IN_DIM + col] = s;
}

__global__ __launch_bounds__(256) void colsum_final(const double* __restrict__ part,
                                                    float* __restrict__ cs) {
    int col = blockIdx.x * 256 + threadIdx.x;
    double s = 0.0;
    for (int r = 0; r < 128; ++r) s += part[(size_t)r * IN_DIM + col];
    cs[col] = (float)s;
}

// ---------------------------------------------------------------------------
// K3: per-row top-128 of |x*colsum| via 4-pass radix select, exact ties
// (lowest index first), write masked x as bf16. One 256-thread block per row.
// ---------------------------------------------------------------------------
__global__ __launch_bounds__(256) void topk_mask(const float* __restrict__ x,
                                                 const float* __restrict__ cs,
                                                 u16* __restrict__ xz) {
    __shared__ uint32_t hist[256];
    __shared__ uint32_t suf[256];
    __shared__ uint32_t s_scan[256];
    __shared__ uint32_t s_prefix, s_krem;

    const int b = blockIdx.x, t = threadIdx.x;
    const float4* xrow = (const float4*)(x + (size_t)b * IN_DIM);
    const float4* csv  = (const float4*)cs;

    float    xr[16];
    uint32_t ul[16];
#pragma unroll
    for (int q = 0; q < 4; ++q) {
        float4 xv = xrow[t * 4 + q];
        float4 cv = csv[t * 4 + q];
        xr[q*4+0] = xv.x; xr[q*4+1] = xv.y; xr[q*4+2] = xv.z; xr[q*4+3] = xv.w;
        ul[q*4+0] = __builtin_bit_cast(uint32_t, xv.x * cv.x) & 0x7fffffffu;
        ul[q*4+1] = __builtin_bit_cast(uint32_t, xv.y * cv.y) & 0x7fffffffu;
        ul[q*4+2] = __builtin_bit_cast(uint32_t, xv.z * cv.z) & 0x7fffffffu;
        ul[q*4+3] = __builtin_bit_cast(uint32_t, xv.w * cv.w) & 0x7fffffffu;
    }
    if (t == 0) { s_prefix = 0u; s_krem = K_SEL; }
    __syncthreads();

#pragma unroll
    for (int p = 3; p >= 0; --p) {
        const int sh = p * 8;
        const uint32_t hi_mask = (p == 3) ? 0u : (0xFFFFFFFFu << (sh + 8));
        const uint32_t prefix = s_prefix;
        const uint32_t krem   = s_krem;
        hist[t] = 0u;
        __syncthreads();
#pragma unroll
        for (int j = 0; j < 16; ++j) {
            uint32_t u = ul[j];
            if ((u & hi_mask) == (prefix & hi_mask))
                atomicAdd(&hist[(u >> sh) & 255u], 1u);
        }
        __syncthreads();
        uint32_t mine = hist[t];
        suf[t] = mine;
        __syncthreads();
#pragma unroll
        for (int off = 1; off < 256; off <<= 1) {
            uint32_t other = (t + off < 256) ? suf[t + off] : 0u;
            __syncthreads();
            mine += other;
            suf[t] = mine;
            __syncthreads();
        }
        uint32_t mysuf   = suf[t];
        uint32_t nextsuf = (t < 255) ? suf[t + 1] : 0u;
        if (mysuf >= krem && (t == 255 || nextsuf < krem)) {
            s_prefix = prefix | ((uint32_t)t << sh);
            s_krem   = krem - nextsuf;
        }
        __syncthreads();
    }
    const uint32_t T       = s_prefix;
    const uint32_t need_eq = s_krem;

    int cnt = 0;
#pragma unroll
    for (int j = 0; j < 16; ++j) cnt += (ul[j] == T) ? 1 : 0;
    s_scan[t] = (uint32_t)cnt;
    __syncthreads();
    uint32_t inc = (uint32_t)cnt;
#pragma unroll
    for (int off = 1; off < 256; off <<= 1) {
        uint32_t other = (t >= off) ? s_scan[t - off] : 0u;
        __syncthreads();
        inc += other;
        s_scan[t] = inc;
        __syncthreads();
    }
    const int base = (int)(inc - (uint32_t)cnt);

    union { u16 us[16]; uint4 v[2]; } ob;
    int eqseen = 0;
#pragma unroll
    for (int j = 0; j < 16; ++j) {
        uint32_t u = ul[j];
        bool drop = (u > T);
        if (u == T) {
            if (base + eqseen < (int)need_eq) drop = true;
            ++eqseen;
        }
        ob.us[j] = drop ? (u16)0 : f2bf(xr[j]);
    }
    uint4* dst = (uint4*)(xz + (size_t)b * IN_DIM + t * 16);
    dst[0] = ob.v[0];
    dst[1] = ob.v[1];
}

// ---------------------------------------------------------------------------
// K4: bf16 GEMM C = A @ B^T, 256x256 tile, BK=64, 8 waves (2Mx4N), m201-style
// quadrant phases with register fragment reuse (24 ds_read/tile/wave):
//   p0: read A-half0 (8) + B-half0 (4)  -> MFMA (qm0,qn0)
//   p1: read B-half1 (4)                -> MFMA (qm0,qn1)  [A regs reused]
//   p2: read A-half1 (8)                -> MFMA (qm1,qn0)  [B0 regs reused]
//   p3: no reads                        -> MFMA (qm1,qn1)  [all regs reused]
// Ring staging 1 region (16KB = 2 gloads)/phase:
//   p0: Bh1(k+1)->bufn | p1: Ah0(k+2)->buf | p2: Bh0(k+2)->buf | p3: Ah1(k+2)->buf
// vmcnt(6) at p3 drains all gloads issued <= p0 => every region of tile k+1
// complete before its first read; each stage target was consumed earlier in
// the same tile (after a barrier). T2 XOR-swizzle (0 conflicts), T5 setprio.
// A region qm packs rows (r>>6)*128 + qm*64 + (r&63); B region qn packs rows
// (r>>5)*64 + qn*32 + (r&31)  (stripe-packed so each region is contiguous).
// ---------------------------------------------------------------------------
#define NT 64

__global__ __launch_bounds__(512, 2) void gemm_8ph(const u16* __restrict__ A,
                                                   const u16* __restrict__ Bm,
                                                   float* __restrict__ C) {
    __shared__ u16 lds_[65536];   // 128 KB

    const int bid = blockIdx.x;
    const int swz = (bid & 7) * 32 + (bid >> 3);   // 256 blocks, 8 XCDs
    const int m0 = (swz >> 4) * 256, n0 = (swz & 15) * 256;

    const int t = threadIdx.x;
    const int w = t >> 6, l = t & 63;
    const int lr = l & 15, lk = l >> 4;
    const int wm = w >> 2, wn = w & 3;

    const int cswz = ((t & 7) ^ ((t >> 3) & 7)) * 8;   // staging src col (elems)
    const int c0   = (lk ^ (lr & 7)) * 8;              // swizzled read col, ks=0

    f32x4 acc[8][4];
#pragma unroll
    for (int i = 0; i < 8; ++i)
#pragma unroll
        for (int j = 0; j < 4; ++j) acc[i][j] = f32x4{0.f, 0.f, 0.f, 0.f};

#define GLOAD(g, off_bytes)                                                     \
    __builtin_amdgcn_global_load_lds(                                           \
        (const __attribute__((address_space(1))) void*)(g),                     \
        (__attribute__((address_space(3))) void*)(((char*)lds_) + (off_bytes)), \
        16, 0, 0)
#define MFMA_(d, va, vb) d = __builtin_amdgcn_mfma_f32_16x16x32_bf16(va, vb, d, 0, 0, 0)

    // stage A region qm (packed rows g*128+qm*64+(t>>3), 16KB = 2 gloads)
    auto stA = [&](int b, int qm, int kt) {
#pragma unroll
        for (int g = 0; g < 2; ++g)
            GLOAD(A + (size_t)(m0 + g * 128 + qm * 64 + (t >> 3)) * IN_DIM + kt + cswz,
                  b * 65536 + qm * 16384 + g * 8192 + t * 16);
    };
    // stage B region qn (packed rows (g*2+(t>>8))*64+qn*32+((t>>3)&31))
    auto stB = [&](int b, int qn, int kt) {
#pragma unroll
        for (int g = 0; g < 2; ++g)
            GLOAD(Bm + (size_t)(n0 + (g * 2 + (t >> 8)) * 64 + qn * 32 + ((t >> 3) & 31)) * IN_DIM + kt + cswz,
                  b * 65536 + 32768 + qn * 16384 + g * 8192 + t * 16);
    };

    // prologue: tile0 (8 gloads) + tile1 {Ah0,Bh0,Ah1} (6); drain tile0
    stA(0, 0, 0); stB(0, 0, 0); stA(0, 1, 0); stB(0, 1, 0);
    stA(1, 0, 64); stB(1, 0, 64); stA(1, 1, 64);
    asm volatile("s_waitcnt vmcnt(6)" ::: "memory");
    __builtin_amdgcn_s_barrier();
    asm volatile("" ::: "memory");

    for (int k = 0; k < NT; ++k) {
        const int buf = k & 1, bufn = buf ^ 1;
        const int kt1 = (k + 1 < NT ? k + 1 : NT - 1) * 64;
        const int kt2 = (k + 2 < NT ? k + 2 : NT - 1) * 64;
        const int aB = buf * 32768 + (wm * 64 + lr) * 64;           // +qm*8192+mi*1024
        const int bB = buf * 32768 + 16384 + (wn * 32 + lr) * 64;   // +qn*8192+ni*1024

        bf16x8 a[4][2], b0[2][2], b1[2][2];

        // ---- p0: read A-half0 + B-half0; stage Bh1(k+1)->bufn; MFMA (0,0) ----
#pragma unroll
        for (int mi = 0; mi < 4; ++mi) {
            a[mi][0] = *(const bf16x8*)&lds_[aB + mi * 1024 + c0];
            a[mi][1] = *(const bf16x8*)&lds_[aB + mi * 1024 + (c0 ^ 32)];
        }
#pragma unroll
        for (int ni = 0; ni < 2; ++ni) {
            b0[ni][0] = *(const bf16x8*)&lds_[bB + ni * 1024 + c0];
            b0[ni][1] = *(const bf16x8*)&lds_[bB + ni * 1024 + (c0 ^ 32)];
        }
        stB(bufn, 1, kt1);
        asm volatile("s_waitcnt lgkmcnt(8)" ::: "memory");
        __builtin_amdgcn_s_barrier();
        asm volatile("s_waitcnt lgkmcnt(0)" ::: "memory");
        __builtin_amdgcn_sched_barrier(0);
        __builtin_amdgcn_s_setprio(1);
#pragma unroll
        for (int mi = 0; mi < 4; ++mi)
#pragma unroll
            for (int ni = 0; ni < 2; ++ni) {
                MFMA_(acc[mi][ni], a[mi][0], b0[ni][0]);
                MFMA_(acc[mi][ni], a[mi][1], b0[ni][1]);
            }
        __builtin_amdgcn_s_setprio(0);
        __builtin_amdgcn_sched_barrier(0);
        asm volatile("" ::: "memory");
        __builtin_amdgcn_s_barrier();
        asm volatile("" ::: "memory");

        // ---- p1: read B-half1; stage Ah0(k+2)->buf; MFMA (0,1) ----
#pragma unroll
        for (int ni = 0; ni < 2; ++ni) {
            b1[ni][0] = *(const bf16x8*)&lds_[bB + 8192 + ni * 1024 + c0];
            b1[ni][1] = *(const bf16x8*)&lds_[bB + 8192 + ni * 1024 + (c0 ^ 32)];
        }
        stA(buf, 0, kt2);
        asm volatile("" ::: "memory");
        __builtin_amdgcn_s_barrier();
        asm volatile("s_waitcnt lgkmcnt(0)" ::: "memory");
        __builtin_amdgcn_sched_barrier(0);
        __builtin_amdgcn_s_setprio(1);
#pragma unroll
        for (int mi = 0; mi < 4; ++mi)
#pragma unroll
            for (int ni = 0; ni < 2; ++ni) {
                MFMA_(acc[mi][2 + ni], a[mi][0], b1[ni][0]);
                MFMA_(acc[mi][2 + ni], a[mi][1], b1[ni][1]);
            }
        __builtin_amdgcn_s_setprio(0);
        __builtin_amdgcn_sched_barrier(0);
        asm volatile("" ::: "memory");
        __builtin_amdgcn_s_barrier();
        asm volatile("" ::: "memory");

        // ---- p2: read A-half1; stage Bh0(k+2)->buf; MFMA (1,0) ----
#pragma unroll
        for (int mi = 0; mi < 4; ++mi) {
            a[mi][0] = *(const bf16x8*)&lds_[aB + 8192 + mi * 1024 + c0];
            a[mi][1] = *(const bf16x8*)&lds_[aB + 8192 + mi * 1024 + (c0 ^ 32)];
        }
        stB(buf, 0, kt2);
        asm volatile("" ::: "memory");
        __builtin_amdgcn_s_barrier();
        asm volatile("s_waitcnt lgkmcnt(0)" ::: "memory");
        __builtin_amdgcn_sched_barrier(0);
        __builtin_amdgcn_s_setprio(1);
#pragma unroll
        for (int mi = 0; mi < 4; ++mi)
#pragma unroll
            for (int ni = 0; ni < 2; ++ni) {
                MFMA_(acc[4 + mi][ni], a[mi][0], b0[ni][0]);
                MFMA_(acc[4 + mi][ni], a[mi][1], b0[ni][1]);
            }
        __builtin_amdgcn_s_setprio(0);
        __builtin_amdgcn_sched_barrier(0);
        asm volatile("" ::: "memory");
        __builtin_amdgcn_s_barrier();
        asm volatile("" ::: "memory");

        // ---- p3 (tail): stage Ah1(k+2)->buf; MFMA (1,1) regs-only; vmcnt(6) ----
        stA(buf, 1, kt2);
        asm volatile("" ::: "memory");
        __builtin_amdgcn_s_setprio(1);
#pragma unroll
        for (int mi = 0; mi < 4; ++mi)
#pragma unroll
            for (int ni = 0; ni < 2; ++ni) {
                MFMA_(acc[4 + mi][2 + ni], a[mi][0], b1[ni][0]);
                MFMA_(acc[4 + mi][2 + ni], a[mi][1], b1[ni][1]);
            }
        __builtin_amdgcn_s_setprio(0);
        __builtin_amdgcn_sched_barrier(0);
        asm volatile("s_waitcnt vmcnt(6)" ::: "memory");
        __builtin_amdgcn_s_barrier();
        asm volatile("" ::: "memory");
    }
#undef GLOAD
#undef MFMA_

    // epilogue: C/D layout col = lane&15, row = (lane>>4)*4 + r
#pragma unroll
    for (int gmi = 0; gmi < 8; ++gmi)
#pragma unroll
        for (int ni = 0; ni < 4; ++ni)
#pragma unroll
            for (int r = 0; r < 4; ++r) {
                int row = m0 + wm * 128 + (gmi >> 2) * 64 + (gmi & 3) * 16 + lk * 4 + r;
                int col = n0 + wn * 64 + ni * 16 + lr;
                C[(size_t)row * OUT_DIM + col] = acc[gmi][ni][r];
            }
}

// ---------------------------------------------------------------------------
extern "C" void kernel_launch(void* const* d_in, const int* in_sizes, int n_in,
                              void* d_out, int out_size, void* d_ws, size_t ws_size,
                              hipStream_t stream) {
    const float* x = (const float*)d_in[0];
    const float* W = (const float*)d_in[1];
    float* out = (float*)d_out;

    char* ws = (char*)d_ws;
    u16*    Wb   = (u16*)ws;                                   // 32 MB bf16 W
    u16*    xz   = (u16*)(ws + (size_t)32 * 1024 * 1024);      // 32 MB bf16 masked x
    float*  cs   = (float*)(ws + (size_t)64 * 1024 * 1024);    // 16 KB colsum
    double* part = (double*)d_out;  // 4 MB partials, consumed before gemm writes

    colsum_conv<<<2048, 256, 0, stream>>>(W, part, Wb);
    colsum_final<<<16, 256, 0, stream>>>(part, cs);
    topk_mask<<<4096, 256, 0, stream>>>(x, cs, xz);
    gemm_8ph<<<256, 512, 0, stream>>>(xz, Wb, out);
}